// Round 2
// baseline (22321.770 us; speedup 1.0000x reference)
//
#include <hip/hip_runtime.h>

#define NB 16
#define NN 307
#define NI 11
#define NH 64

// ws offsets in floats (all 1024-float aligned for float4 safety)
#define OFF_A      0u
#define OFF_AGCW   95232u      // A: 94249 -> pad 95232
#define OFF_AGCB   2610176u    // agcW: 2514944
#define OFF_H      2630656u    // agcb: 19648 -> pad 20480
#define OFF_Z      2945024u
#define OFF_KH     3259392u
#define OFF_KZ     3573760u
#define OFF_ACCH   3888128u
#define OFF_ACCZ   4202496u
#define OFF_X      4516864u
// end: 4831232 floats = 19.3 MB

__device__ __forceinline__ float tanh_fast(float x){
    // tanh(x) = 1 - 2/(exp(2x)+1); exp->v_exp_f32, rcp->v_rcp_f32 (~1e-6 abs err)
    float e = __expf(2.0f * x);
    return 1.0f - 2.0f * __builtin_amdgcn_rcpf(e + 1.0f);
}

// ---------- precompute kernels ----------

// A = softmax(relu(gE @ gE^T), axis=1) ; one wave per row n
__global__ void kA(const float* __restrict__ gE, float* __restrict__ A){
    int n = blockIdx.x;
    int lane = threadIdx.x;
    float en[8];
#pragma unroll
    for (int d = 0; d < 8; d++) en[d] = gE[n*8 + d];
    float vals[5];
    float mx = -1e30f;
#pragma unroll
    for (int ii = 0; ii < 5; ii++){
        int m = lane + 64*ii;
        float v = -1e30f;
        if (m < NN){
            float a = 0.f;
#pragma unroll
            for (int d = 0; d < 8; d++) a += en[d] * gE[m*8 + d];
            v = fmaxf(a, 0.f);
        }
        vals[ii] = v;
        mx = fmaxf(mx, v);
    }
#pragma unroll
    for (int off = 32; off >= 1; off >>= 1) mx = fmaxf(mx, __shfl_xor(mx, off, 64));
    float s = 0.f;
#pragma unroll
    for (int ii = 0; ii < 5; ii++){
        int m = lane + 64*ii;
        if (m < NN){ vals[ii] = __expf(vals[ii] - mx); s += vals[ii]; }
    }
#pragma unroll
    for (int off = 32; off >= 1; off >>= 1) s += __shfl_xor(s, off, 64);
    float inv = 1.f / s;
#pragma unroll
    for (int ii = 0; ii < 5; ii++){
        int m = lane + 64*ii;
        if (m < NN) A[n*NN + m] = vals[ii] * inv;
    }
}

// agcW[n,k,i,o] = sum_d gE[n,d]*gWpool[d,k,i,o]   (flat: n*8192 + k*4096 + i*64 + o)
__global__ void kAgcW(const float* __restrict__ gE, const float* __restrict__ gWpool,
                      float* __restrict__ agcW){
    int gid = blockIdx.x*256 + threadIdx.x;   // exactly 2514944
    int o = gid & 63;
    int i = (gid >> 6) & 63;
    int k = (gid >> 12) & 1;
    int n = gid >> 13;
    float acc = 0.f;
#pragma unroll
    for (int d = 0; d < 8; d++) acc += gE[n*8 + d] * gWpool[((d*2 + k)*64 + i)*64 + o];
    agcW[gid] = acc;
}

__global__ void kAgcB(const float* __restrict__ gE, const float* __restrict__ gbpool,
                      float* __restrict__ agcb){
    int gid = blockIdx.x*256 + threadIdx.x;
    if (gid >= NN*64) return;
    int o = gid & 63;
    int n = gid >> 6;
    float acc = 0.f;
#pragma unroll
    for (int d = 0; d < 8; d++) acc += gE[n*8 + d] * gbpool[d*64 + o];
    agcb[gid] = acc;
}

// h0 = x0 @ h_W + h_b ; z0 = x0 @ z_W + z_b  with x0 = coeff_a[:,:,0,:]
__global__ void kInit(const float* __restrict__ ca,
                      const float* __restrict__ hW, const float* __restrict__ hb,
                      const float* __restrict__ zW, const float* __restrict__ zb,
                      float* __restrict__ h, float* __restrict__ z){
    int gid = blockIdx.x*256 + threadIdx.x;   // exactly 314368
    int t = gid & 63;
    int bn = gid >> 6;
    float x0 = ca[bn*NI*2 + 0];
    float x1 = ca[bn*NI*2 + 1];
    h[gid] = x0*hW[t] + x1*hW[64 + t] + hb[t];
    z[gid] = x0*zW[t] + x1*zW[64 + t] + zb[t];
}

// ---------- per-stage kernel 1: stage input, func_f MLP, dh(=kh), g-input x ----------
// one wave per (b,n); 4 waves/block; grid 1228 (exact)
__global__ __launch_bounds__(256) void K1(
    float* __restrict__ h, const float* __restrict__ z,
    float* __restrict__ kh, const float* __restrict__ kz,
    float* __restrict__ acch, float* __restrict__ x,
    const float* __restrict__ Cb, const float* __restrict__ Cc, const float* __restrict__ Cd,
    const float* __restrict__ WfIn, const float* __restrict__ fbIn,
    const float* __restrict__ WfMid, const float* __restrict__ fbMid,
    const float* __restrict__ WfOut, const float* __restrict__ fbOut,
    const float* __restrict__ WgIn, const float* __restrict__ gbIn,
    int stage, float acoef, int idx, float frac)
{
    __shared__ float4 bufA[4][16];
    __shared__ float4 bufB[4][16];
    __shared__ float4 bufZ[4][16];
    int tid = threadIdx.x;
    int wv = tid >> 6;
    int lane = tid & 63;
    int bn = blockIdx.x*4 + wv;
    int base = bn*64 + lane;

    float hv = h[base];
    float zv = z[base];
    float sih = hv, siz = zv;
    if (stage > 0){ sih += acoef * kh[base]; siz += acoef * kz[base]; }
    ((float*)&bufA[wv][0])[lane] = sih;
    ((float*)&bufZ[wv][0])[lane] = siz;
    __syncthreads();

    // u1 = relu(sih @ WfIn + fbIn)
    float u = fbIn[lane];
#pragma unroll
    for (int k4 = 0; k4 < 16; k4++){
        float4 s4 = bufA[wv][k4];
        int k = k4*4;
        u += s4.x*WfIn[(k+0)*64 + lane];
        u += s4.y*WfIn[(k+1)*64 + lane];
        u += s4.z*WfIn[(k+2)*64 + lane];
        u += s4.w*WfIn[(k+3)*64 + lane];
    }
    u = fmaxf(u, 0.f);
    ((float*)&bufB[wv][0])[lane] = u;
    __syncthreads();

    // u2 = relu(u1 @ WfMid + fbMid)
    float u2 = fbMid[lane];
#pragma unroll
    for (int k4 = 0; k4 < 16; k4++){
        float4 s4 = bufB[wv][k4];
        int k = k4*4;
        u2 += s4.x*WfMid[(k+0)*64 + lane];
        u2 += s4.y*WfMid[(k+1)*64 + lane];
        u2 += s4.z*WfMid[(k+2)*64 + lane];
        u2 += s4.w*WfMid[(k+3)*64 + lane];
    }
    u2 = fmaxf(u2, 0.f);
    ((float*)&bufA[wv][0])[lane] = u2;   // reuse bufA (sih consumed)
    __syncthreads();

    // f_v[lane, 0..1] = tanh(u2 @ WfOut + fbOut) ; x = relu(siz @ WgIn + gbIn)
    float f0 = fbOut[lane*2 + 0];
    float f1 = fbOut[lane*2 + 1];
    float xv = gbIn[lane];
#pragma unroll
    for (int k4 = 0; k4 < 16; k4++){
        float4 s4 = bufA[wv][k4];
        float4 z4 = bufZ[wv][k4];
        int k = k4*4;
        f0 += s4.x*WfOut[(k+0)*128 + lane*2+0]; f1 += s4.x*WfOut[(k+0)*128 + lane*2+1];
        f0 += s4.y*WfOut[(k+1)*128 + lane*2+0]; f1 += s4.y*WfOut[(k+1)*128 + lane*2+1];
        f0 += s4.z*WfOut[(k+2)*128 + lane*2+0]; f1 += s4.z*WfOut[(k+2)*128 + lane*2+1];
        f0 += s4.w*WfOut[(k+3)*128 + lane*2+0]; f1 += s4.w*WfOut[(k+3)*128 + lane*2+1];
        xv += z4.x*WgIn[(k+0)*64 + lane];
        xv += z4.y*WgIn[(k+1)*64 + lane];
        xv += z4.z*WgIn[(k+2)*64 + lane];
        xv += z4.w*WgIn[(k+3)*64 + lane];
    }
    f0 = tanh_fast(f0);
    f1 = tanh_fast(f1);

    // spline derivative dX (wave-uniform loads)
    int cb = (bn*NI + idx)*2;
    float b0 = Cb[cb], b1 = Cb[cb+1];
    float c0 = Cc[cb], c1 = Cc[cb+1];
    float d0 = Cd[cb], d1 = Cd[cb+1];
    float dx0 = b0 + (c0 + d0*frac)*frac;
    float dx1 = b1 + (c1 + d1*frac)*frac;

    float khv = f0*dx0 + f1*dx1;   // dh
    kh[base] = khv;
    if (stage == 0)      acch[base] = khv;
    else if (stage < 3)  acch[base] += 2.f*khv;
    else                 h[base] = hv + (1.f/6.f)*(acch[base] + khv);

    x[base] = fmaxf(xv, 0.f);
}

// ---------- per-stage kernel 2: graph mix, adaptive conv, fused gv@dh, z bookkeeping ----------
// block: 256 threads, handles 8 nodes of one batch b; grid 16*39 = 624
// Phase C register budget: acc[8] + w[16] + transient y4 -> ~90 VGPR, NO spill
// (R0 had w[64]/thread -> 256 VGPR + 170 MB/dispatch scratch spill traffic)
__global__ __launch_bounds__(256) void K2(
    float* __restrict__ z, const float* __restrict__ kh, float* __restrict__ kz,
    float* __restrict__ accz, const float* __restrict__ x,
    const float* __restrict__ A, const float* __restrict__ agcW, const float* __restrict__ agcb,
    const float* __restrict__ WgOut, const float* __restrict__ gbOut,
    int stage)
{
    __shared__ float  xs[64][64];     // x chunk [m][o]
    __shared__ float  as_[8][64];     // A[n0+r][m-chunk]
    __shared__ float4 xlds[8][16];    // x of own rows
    __shared__ float4 xglds[8][16];   // A-mixed x
    __shared__ float  khlds[8][64];
    __shared__ float4 ylds[8][16];
    __shared__ float  dzlds[8][64];

    int tid = threadIdx.x;
    int lane = tid & 63;
    int wv = tid >> 6;                 // row group: rows wv and wv+4
    int b = blockIdx.x / 39;
    int tile = blockIdx.x % 39;
    int n0 = tile*8;
    int nr = min(8, NN - n0);
    int o = lane;

    // preload own-row x and kh
#pragma unroll
    for (int rh = 0; rh < 2; rh++){
        int r = wv + rh*4;
        int ne = min(n0 + r, NN - 1);
        ((float*)&xlds[r][0])[o] = x[(b*NN + ne)*64 + o];
        khlds[r][o]              = kh[(b*NN + ne)*64 + o];
    }

    // Phase A: xg[r] = sum_m A[n0+r, m] * x[b, m, :]
    float xg0 = 0.f, xg1 = 0.f;
    for (int ch = 0; ch < 5; ch++){
        int m0 = ch*64;
        int mc = min(64, NN - m0);
        for (int mi = wv; mi < mc; mi += 4)
            xs[mi][o] = x[(b*NN + m0 + mi)*64 + o];
#pragma unroll
        for (int e2 = 0; e2 < 2; e2++){
            int e = tid + e2*256;
            int r = e >> 6, m = e & 63;
            int n = n0 + r;
            as_[r][m] = (m < mc && n < NN) ? A[n*NN + m0 + m] : 0.f;
        }
        __syncthreads();
        for (int m = 0; m < mc; m++){
            float xv = xs[m][o];
            xg0 += as_[wv][m] * xv;
            xg1 += as_[wv+4][m] * xv;
        }
        __syncthreads();
    }
    ((float*)&xglds[wv][0])[o]   = xg0;
    ((float*)&xglds[wv+4][0])[o] = xg1;
    __syncthreads();

    // Phase B: y[r,o] = relu( sum_i x*agcW[n,0,i,o] + xg*agcW[n,1,i,o] + agcb[n,o] )
#pragma unroll
    for (int rh = 0; rh < 2; rh++){
        int r = wv + rh*4;
        if (r < nr){
            int n = n0 + r;
            float acc = agcb[n*64 + o];
            const float* W0 = agcW + (size_t)(n*2 + 0)*4096;
            const float* W1 = agcW + (size_t)(n*2 + 1)*4096;
#pragma unroll
            for (int i4 = 0; i4 < 16; i4++){
                float4 xi  = xlds[r][i4];
                float4 xgi = xglds[r][i4];
                int i = i4*4;
                acc += xi.x*W0[(i+0)*64+o] + xi.y*W0[(i+1)*64+o] + xi.z*W0[(i+2)*64+o] + xi.w*W0[(i+3)*64+o];
                acc += xgi.x*W1[(i+0)*64+o] + xgi.y*W1[(i+1)*64+o] + xgi.z*W1[(i+2)*64+o] + xgi.w*W1[(i+3)*64+o];
            }
            ((float*)&ylds[r][0])[o] = fmaxf(acc, 0.f);
        } else {
            ((float*)&ylds[r][0])[o] = 0.f;   // tail rows: keep Phase C inputs finite
        }
    }
    __syncthreads();

    // Phase C: dz[r,i] = sum_j tanh( y[r] . WgOut[:, i*64+j] + gbOut ) * kh[r,j]
    // k-chunked: w[16] live at a time, reused across 8 rows; acc[8] across chunks.
    for (int q = 0; q < 16; q++){
        int oo = (q << 8) + tid;       // column of WgOut; i = 4q+wv, j = lane
        float gb = gbOut[oo];
        float acc[8];
#pragma unroll
        for (int r = 0; r < 8; r++) acc[r] = gb;
        const float* Wq = WgOut + oo;
#pragma unroll
        for (int kc = 0; kc < 4; kc++){
            float w[16];
#pragma unroll
            for (int j = 0; j < 16; j++) w[j] = Wq[(kc*16 + j)*4096];
#pragma unroll
            for (int r = 0; r < 8; r++){
                float4 y0 = ylds[r][kc*4+0];
                float4 y1 = ylds[r][kc*4+1];
                float4 y2 = ylds[r][kc*4+2];
                float4 y3 = ylds[r][kc*4+3];
                acc[r] += y0.x*w[0]  + y0.y*w[1]  + y0.z*w[2]  + y0.w*w[3]
                        + y1.x*w[4]  + y1.y*w[5]  + y1.z*w[6]  + y1.w*w[7]
                        + y2.x*w[8]  + y2.y*w[9]  + y2.z*w[10] + y2.w*w[11]
                        + y3.x*w[12] + y3.y*w[13] + y3.z*w[14] + y3.w*w[15];
            }
        }
#pragma unroll
        for (int r = 0; r < 8; r++){
            float tv = tanh_fast(acc[r]);
            float cc = tv * khlds[r][lane];
#pragma unroll
            for (int off = 32; off >= 1; off >>= 1) cc += __shfl_xor(cc, off, 64);
            if (lane == 0) dzlds[r][(q << 2) + wv] = cc;
        }
    }
    __syncthreads();

    // Phase D: write kz (=dz) + RK4 z bookkeeping
    for (int e = tid; e < nr*64; e += 256){
        int r = e >> 6, i = e & 63;
        int addr = (b*NN + n0 + r)*64 + i;
        float v = dzlds[r][i];
        kz[addr] = v;
        if (stage == 0)      accz[addr] = v;
        else if (stage < 3)  accz[addr] += 2.f*v;
        else                 z[addr] = z[addr] + (1.f/6.f)*(accz[addr] + v);
    }
}

// ---------- output ----------
__global__ __launch_bounds__(256) void kOut(const float* __restrict__ z,
                                            const float* __restrict__ convW,
                                            const float* __restrict__ convB,
                                            float* __restrict__ out){
    int gid = blockIdx.x*256 + threadIdx.x;
    if (gid >= NB*NN) return;
    int b = gid / NN, n = gid % NN;
    float zr[64];
    const float4* zp = (const float4*)(z + (size_t)gid*64);
#pragma unroll
    for (int k4 = 0; k4 < 16; k4++){
        float4 v = zp[k4];
        zr[k4*4+0] = v.x; zr[k4*4+1] = v.y; zr[k4*4+2] = v.z; zr[k4*4+3] = v.w;
    }
#pragma unroll
    for (int o = 0; o < 12; o++){
        float acc = convB[o];
#pragma unroll
        for (int hh = 0; hh < 64; hh++) acc += zr[hh]*convW[o*64 + hh];
        out[(b*12 + o)*NN + n] = acc;
    }
}

extern "C" void kernel_launch(void* const* d_in, const int* in_sizes, int n_in,
                              void* d_out, int out_size, void* d_ws, size_t ws_size,
                              hipStream_t stream)
{
    const float* coeff_a = (const float*)d_in[0];
    const float* coeff_b = (const float*)d_in[1];
    const float* coeff_c = (const float*)d_in[2];
    const float* coeff_d = (const float*)d_in[3];
    // d_in[4] = times (arange(12), folded into host idx/frac)
    const float* hW     = (const float*)d_in[5];
    const float* hb     = (const float*)d_in[6];
    const float* zW     = (const float*)d_in[7];
    const float* zb     = (const float*)d_in[8];
    const float* WfIn   = (const float*)d_in[9];
    const float* fbIn   = (const float*)d_in[10];
    const float* WfMid  = (const float*)d_in[11];
    const float* fbMid  = (const float*)d_in[12];
    const float* WfOut  = (const float*)d_in[13];
    const float* fbOut  = (const float*)d_in[14];
    const float* WgIn   = (const float*)d_in[15];
    const float* gbIn   = (const float*)d_in[16];
    const float* gE     = (const float*)d_in[17];
    const float* gWpool = (const float*)d_in[18];
    const float* gbpool = (const float*)d_in[19];
    const float* WgOut  = (const float*)d_in[20];
    const float* gbOut  = (const float*)d_in[21];
    const float* convW  = (const float*)d_in[22];
    const float* convB  = (const float*)d_in[23];

    float* ws   = (float*)d_ws;
    float* A    = ws + OFF_A;
    float* agcW = ws + OFF_AGCW;
    float* agcb = ws + OFF_AGCB;
    float* h    = ws + OFF_H;
    float* z    = ws + OFF_Z;
    float* kh   = ws + OFF_KH;
    float* kz   = ws + OFF_KZ;
    float* acch = ws + OFF_ACCH;
    float* accz = ws + OFF_ACCZ;
    float* x    = ws + OFF_X;
    float* out  = (float*)d_out;

    kA    <<<NN,   64,  0, stream>>>(gE, A);
    kAgcW <<<9824, 256, 0, stream>>>(gE, gWpool, agcW);
    kAgcB <<<77,   256, 0, stream>>>(gE, gbpool, agcb);
    kInit <<<1228, 256, 0, stream>>>(coeff_a, hW, hb, zW, zb, h, z);

    const float acoef[4] = {0.f, 0.5f, 0.5f, 1.f};
    for (int step = 0; step < 11; step++){
        for (int s = 0; s < 4; s++){
            int idx; float frac;
            if (s == 0)      { idx = step;     frac = 0.f;  }
            else if (s < 3)  { idx = step;     frac = 0.5f; }
            else if (step<10){ idx = step + 1; frac = 0.f;  }
            else             { idx = 10;       frac = 1.f;  }
            K1<<<1228, 256, 0, stream>>>(h, z, kh, kz, acch, x,
                coeff_b, coeff_c, coeff_d, WfIn, fbIn, WfMid, fbMid,
                WfOut, fbOut, WgIn, gbIn, s, acoef[s], idx, frac);
            K2<<<624, 256, 0, stream>>>(z, kh, kz, accz, x, A, agcW, agcb,
                WgOut, gbOut, s);
        }
    }
    kOut<<<20, 256, 0, stream>>>(z, convW, convB, out);
}

// Round 3
// 3860.441 us; speedup vs baseline: 5.7822x; 5.7822x over previous
//
#include <hip/hip_runtime.h>

#define NB 16
#define NN 307
#define NI 11

typedef __attribute__((ext_vector_type(8))) short bf16x8;
typedef __attribute__((ext_vector_type(4))) float f32x4;

// ws offsets in FLOAT units
#define OFF_ABF    0u          // 320x320 bf16 = 51200 fl
#define OFF_AGCWT  51200u      // 307*64*128 bf16 = 1257472 fl
#define OFF_AGCB   1308672u    // 307*64 f32 -> pad 20480
#define OFF_WT     1329152u    // 4096*64 bf16 = 131072 fl
#define OFF_H      1460224u    // each state: 16*307*64 = 314368 fl
#define OFF_Z      1774592u
#define OFF_KH     2088960u
#define OFF_KZ     2403328u
#define OFF_ACCH   2717696u
#define OFF_ACCZ   3032064u
#define OFF_XBF    3346432u    // 320*16*64 bf16 = 163840 fl
#define OFF_XGBF   3510272u    // end 3674112 fl = 14.7 MB

__device__ __forceinline__ float tanh_fast(float x){
    float e = __expf(2.0f * x);
    return 1.0f - 2.0f * __builtin_amdgcn_rcpf(e + 1.0f);
}
__device__ __forceinline__ unsigned short f2bf(float f){
    unsigned u = __builtin_bit_cast(unsigned, f);
    unsigned r = u + 0x7FFFu + ((u >> 16) & 1u);
    return (unsigned short)(r >> 16);
}

// ---------- precompute ----------

// Abf[n][m] = bf16(softmax(relu(gE gE^T))) padded to 320x320 with zeros
__global__ void kA(const float* __restrict__ gE, unsigned short* __restrict__ Abf){
    int n = blockIdx.x;            // grid 320, 64 threads
    int lane = threadIdx.x;
    if (n >= NN){
#pragma unroll
        for (int ii = 0; ii < 5; ii++) Abf[n*320 + lane + 64*ii] = 0;
        return;
    }
    float en[8];
#pragma unroll
    for (int d = 0; d < 8; d++) en[d] = gE[n*8 + d];
    float vals[5];
    float mx = -1e30f;
#pragma unroll
    for (int ii = 0; ii < 5; ii++){
        int m = lane + 64*ii;
        float v = -1e30f;
        if (m < NN){
            float a = 0.f;
#pragma unroll
            for (int d = 0; d < 8; d++) a += en[d] * gE[m*8 + d];
            v = fmaxf(a, 0.f);
        }
        vals[ii] = v;
        mx = fmaxf(mx, v);
    }
#pragma unroll
    for (int off = 32; off >= 1; off >>= 1) mx = fmaxf(mx, __shfl_xor(mx, off, 64));
    float s = 0.f;
#pragma unroll
    for (int ii = 0; ii < 5; ii++){
        int m = lane + 64*ii;
        if (m < NN){ vals[ii] = __expf(vals[ii] - mx); s += vals[ii]; }
    }
#pragma unroll
    for (int off = 32; off >= 1; off >>= 1) s += __shfl_xor(s, off, 64);
    float inv = 1.f / s;
#pragma unroll
    for (int ii = 0; ii < 5; ii++){
        int m = lane + 64*ii;
        unsigned short v = 0;
        if (m < NN) v = f2bf(vals[ii] * inv);
        Abf[n*320 + m] = v;
    }
}

// agcWt[n][o][k] bf16, k = kk*64+i in [0,128)
__global__ __launch_bounds__(256) void kAgcWT(const float* __restrict__ gE,
                                              const float* __restrict__ gWpool,
                                              unsigned short* __restrict__ agcWt){
    __shared__ float t[128*65];
    int tid = threadIdx.x;
    int n = blockIdx.x;            // grid 307
    float ge[8];
#pragma unroll
    for (int d = 0; d < 8; d++) ge[d] = gE[n*8 + d];
    for (int it = 0; it < 32; it++){
        int e = it*256 + tid;      // [0,8192)
        int o = e & 63, i = (e >> 6) & 63, kk = e >> 12;
        float acc = 0.f;
#pragma unroll
        for (int d = 0; d < 8; d++) acc += ge[d] * gWpool[((size_t)(d*2 + kk)*64 + i)*64 + o];
        t[(kk*64 + i)*65 + o] = acc;
    }
    __syncthreads();
    for (int it = 0; it < 32; it++){
        int e = it*256 + tid;
        int k = e & 127, o = e >> 7;
        agcWt[((size_t)n*64 + o)*128 + k] = f2bf(t[k*65 + o]);
    }
}

__global__ void kAgcB(const float* __restrict__ gE, const float* __restrict__ gbpool,
                      float* __restrict__ agcb){
    int gid = blockIdx.x*256 + threadIdx.x;
    if (gid >= NN*64) return;
    int o = gid & 63;
    int n = gid >> 6;
    float acc = 0.f;
#pragma unroll
    for (int d = 0; d < 8; d++) acc += gE[n*8 + d] * gbpool[d*64 + o];
    agcb[gid] = acc;
}

// Wtbf[col][k] bf16 (transpose of WgOut[k][col])
__global__ __launch_bounds__(256) void kWt(const float* __restrict__ WgOut,
                                           unsigned short* __restrict__ Wtbf){
    __shared__ float t[64*65];
    int tid = threadIdx.x;
    int c0 = blockIdx.x*64;        // grid 64
    for (int it = 0; it < 16; it++){
        int e = it*256 + tid;
        int k = e >> 6, c = e & 63;
        t[k*65 + c] = WgOut[(size_t)k*4096 + c0 + c];
    }
    __syncthreads();
    for (int it = 0; it < 16; it++){
        int e = it*256 + tid;
        int c = e >> 6, k = e & 63;
        Wtbf[(size_t)(c0 + c)*64 + k] = f2bf(t[k*65 + c]);
    }
}

__global__ void kInit(const float* __restrict__ ca,
                      const float* __restrict__ hW, const float* __restrict__ hb,
                      const float* __restrict__ zW, const float* __restrict__ zb,
                      float* __restrict__ h, float* __restrict__ z){
    int gid = blockIdx.x*256 + threadIdx.x;   // exactly 314368
    int t = gid & 63;
    int bn = gid >> 6;
    float x0 = ca[bn*NI*2 + 0];
    float x1 = ca[bn*NI*2 + 1];
    h[gid] = x0*hW[t] + x1*hW[64 + t] + hb[t];
    z[gid] = x0*zW[t] + x1*zW[64 + t] + zb[t];
}

// ---------- K1: stage input, func_f MLP, kh, g-input x (bf16, node-major) ----------
__global__ __launch_bounds__(256) void K1(
    float* __restrict__ h, const float* __restrict__ z,
    float* __restrict__ kh, const float* __restrict__ kz,
    float* __restrict__ acch, unsigned short* __restrict__ xbf,
    const float* __restrict__ Cb, const float* __restrict__ Cc, const float* __restrict__ Cd,
    const float* __restrict__ WfIn, const float* __restrict__ fbIn,
    const float* __restrict__ WfMid, const float* __restrict__ fbMid,
    const float* __restrict__ WfOut, const float* __restrict__ fbOut,
    const float* __restrict__ WgIn, const float* __restrict__ gbIn,
    int stage, float acoef, int idx, float frac)
{
    __shared__ float4 bufA[4][16];
    __shared__ float4 bufB[4][16];
    __shared__ float4 bufZ[4][16];
    int tid = threadIdx.x;
    int wv = tid >> 6;
    int lane = tid & 63;
    int bn = blockIdx.x*4 + wv;            // b*307 + n
    int base = bn*64 + lane;
    unsigned ub = (unsigned)bn / 307u;
    int b = (int)ub;
    int n = bn - b*307;

    float hv = h[base];
    float zv = z[base];
    float sih = hv, siz = zv;
    if (stage > 0){ sih += acoef * kh[base]; siz += acoef * kz[base]; }
    ((float*)&bufA[wv][0])[lane] = sih;
    ((float*)&bufZ[wv][0])[lane] = siz;
    __syncthreads();

    float u = fbIn[lane];
#pragma unroll
    for (int k4 = 0; k4 < 16; k4++){
        float4 s4 = bufA[wv][k4];
        int k = k4*4;
        u += s4.x*WfIn[(k+0)*64 + lane];
        u += s4.y*WfIn[(k+1)*64 + lane];
        u += s4.z*WfIn[(k+2)*64 + lane];
        u += s4.w*WfIn[(k+3)*64 + lane];
    }
    u = fmaxf(u, 0.f);
    ((float*)&bufB[wv][0])[lane] = u;
    __syncthreads();

    float u2 = fbMid[lane];
#pragma unroll
    for (int k4 = 0; k4 < 16; k4++){
        float4 s4 = bufB[wv][k4];
        int k = k4*4;
        u2 += s4.x*WfMid[(k+0)*64 + lane];
        u2 += s4.y*WfMid[(k+1)*64 + lane];
        u2 += s4.z*WfMid[(k+2)*64 + lane];
        u2 += s4.w*WfMid[(k+3)*64 + lane];
    }
    u2 = fmaxf(u2, 0.f);
    ((float*)&bufA[wv][0])[lane] = u2;
    __syncthreads();

    float f0 = fbOut[lane*2 + 0];
    float f1 = fbOut[lane*2 + 1];
    float xv = gbIn[lane];
#pragma unroll
    for (int k4 = 0; k4 < 16; k4++){
        float4 s4 = bufA[wv][k4];
        float4 z4 = bufZ[wv][k4];
        int k = k4*4;
        f0 += s4.x*WfOut[(k+0)*128 + lane*2+0]; f1 += s4.x*WfOut[(k+0)*128 + lane*2+1];
        f0 += s4.y*WfOut[(k+1)*128 + lane*2+0]; f1 += s4.y*WfOut[(k+1)*128 + lane*2+1];
        f0 += s4.z*WfOut[(k+2)*128 + lane*2+0]; f1 += s4.z*WfOut[(k+2)*128 + lane*2+1];
        f0 += s4.w*WfOut[(k+3)*128 + lane*2+0]; f1 += s4.w*WfOut[(k+3)*128 + lane*2+1];
        xv += z4.x*WgIn[(k+0)*64 + lane];
        xv += z4.y*WgIn[(k+1)*64 + lane];
        xv += z4.z*WgIn[(k+2)*64 + lane];
        xv += z4.w*WgIn[(k+3)*64 + lane];
    }
    f0 = tanh_fast(f0);
    f1 = tanh_fast(f1);

    int cb = (bn*NI + idx)*2;
    float b0 = Cb[cb], b1 = Cb[cb+1];
    float c0 = Cc[cb], c1 = Cc[cb+1];
    float d0 = Cd[cb], d1 = Cd[cb+1];
    float dx0 = b0 + (c0 + d0*frac)*frac;
    float dx1 = b1 + (c1 + d1*frac)*frac;

    float khv = f0*dx0 + f1*dx1;
    kh[base] = khv;
    if (stage == 0)      acch[base] = khv;
    else if (stage < 3)  acch[base] += 2.f*khv;
    else                 h[base] = hv + (1.f/6.f)*(acch[base] + khv);

    xbf[((size_t)n*16 + b)*64 + lane] = f2bf(fmaxf(xv, 0.f));
}

// ---------- KXG: xg = A @ x per batch, MFMA. grid 320 (b*20 + ntile) ----------
__global__ __launch_bounds__(256) void KXG(
    const unsigned short* __restrict__ xbf, const unsigned short* __restrict__ Abf,
    unsigned short* __restrict__ xgbf)
{
    __shared__ unsigned short Xt[64*40];   // [c][m'] pad 40
    int tid = threadIdx.x, lane = tid & 63, wv = tid >> 6;
    int quad = lane >> 4, l15 = lane & 15;
    int b = blockIdx.x / 20, nt = blockIdx.x % 20;
    int n0 = nt*16;
    f32x4 acc = {0.f,0.f,0.f,0.f};
    for (int mt = 0; mt < 10; mt++){
        int m0 = mt*32;
        __syncthreads();
#pragma unroll
        for (int it = 0; it < 8; it++){
            int e = it*256 + tid;
            int c = e & 63, mp = e >> 6;
            int m = m0 + mp;
            unsigned short v = 0;
            if (m < NN) v = xbf[((size_t)m*16 + b)*64 + c];
            Xt[c*40 + mp] = v;
        }
        __syncthreads();
        bf16x8 a  = *(const bf16x8*)(Abf + (size_t)(n0 + l15)*320 + m0 + quad*8);
        bf16x8 bb = *(const bf16x8*)(Xt + (wv*16 + l15)*40 + quad*8);
        acc = __builtin_amdgcn_mfma_f32_16x16x32_bf16(a, bb, acc, 0, 0, 0);
    }
    // D[n'=quad*4+r][c'=l15], wave wv owns c-tile wv*16
#pragma unroll
    for (int r = 0; r < 4; r++){
        int n = n0 + quad*4 + r;
        xgbf[((size_t)n*16 + b)*64 + wv*16 + l15] = f2bf(acc[r]);
    }
}

// ---------- K2g: per-node Y (MFMA) + big GEMM Wt@Y^T + tanh*kh contraction ----------
// grid 77*4 = 308 : nt = blk>>2 (4 nodes), cg = blk&3 (1024 cols)
__global__ __launch_bounds__(256) void K2g(
    float* __restrict__ z, const float* __restrict__ kh,
    float* __restrict__ kz, float* __restrict__ accz,
    const unsigned short* __restrict__ xbf, const unsigned short* __restrict__ xgbf,
    const unsigned short* __restrict__ agcWt, const float* __restrict__ agcb,
    const unsigned short* __restrict__ Wtbf, const float* __restrict__ gbOut,
    int stage)
{
    __shared__ unsigned short Ybf[4*16*72];   // [w][b][k] pad 72
    __shared__ float khl[4*16*68];            // [w][b][j] pad 68
    __shared__ float dzl[4*16*17];            // [w][b][il] pad 17
    int tid = threadIdx.x, lane = tid & 63, wv = tid >> 6;
    int quad = lane >> 4, l15 = lane & 15;
    int nt = blockIdx.x >> 2, cg = blockIdx.x & 3;
    int n0 = nt*4;
    int nw = n0 + wv;
    int n = nw < NN ? nw : NN-1;
    int C0 = cg*1024;

    // khl: lane (quad=part, l15=b) loads 16 floats of kh[b][n][:]
    {
        const float* src = kh + ((size_t)l15*NN + n)*64 + quad*16;
        float* dst = khl + (wv*16 + l15)*68 + quad*16;
#pragma unroll
        for (int u2 = 0; u2 < 4; u2++)
            *(float4*)(dst + u2*4) = *(const float4*)(src + u2*4);
    }

    // Y-compute: Y_n[b][o] = relu(Xcat_n @ agcWt_n + agcb_n)
    const size_t xrow = ((size_t)n*16 + l15)*64;
#pragma unroll
    for (int ot = 0; ot < 4; ot++){
        f32x4 acc = {0.f,0.f,0.f,0.f};
#pragma unroll
        for (int kt = 0; kt < 4; kt++){
            bf16x8 a;
            if (kt < 2) a = *(const bf16x8*)(xbf  + xrow + kt*32 + quad*8);
            else        a = *(const bf16x8*)(xgbf + xrow + (kt-2)*32 + quad*8);
            bf16x8 bb = *(const bf16x8*)(agcWt + ((size_t)n*64 + ot*16 + l15)*128 + kt*32 + quad*8);
            acc = __builtin_amdgcn_mfma_f32_16x16x32_bf16(a, bb, acc, 0, 0, 0);
        }
        float gb = agcb[n*64 + ot*16 + l15];
#pragma unroll
        for (int r = 0; r < 4; r++){
            float v = fmaxf(acc[r] + gb, 0.f);
            Ybf[(wv*16 + quad*4 + r)*72 + ot*16 + l15] = f2bf(v);
        }
    }
    // wave reads only its own Ybf[wv]/khl[wv] -> no block barrier needed here

    // Big GEMM transposed: D[col_local][b]; fuse tanh, *kh, j-reduction
    float pacc = 0.f;
#pragma unroll 1
    for (int ct = 0; ct < 64; ct++){
        int col0 = C0 + ct*16;
        f32x4 acc = {0.f,0.f,0.f,0.f};
#pragma unroll
        for (int kt = 0; kt < 2; kt++){
            bf16x8 a  = *(const bf16x8*)(Wtbf + (size_t)(col0 + l15)*64 + kt*32 + quad*8);
            bf16x8 bb = *(const bf16x8*)(Ybf + (wv*16 + l15)*72 + kt*32 + quad*8);
            acc = __builtin_amdgcn_mfma_f32_16x16x32_bf16(a, bb, acc, 0, 0, 0);
        }
        float4 gb4 = *(const float4*)(gbOut + col0 + quad*4);
        const float* khr = khl + (wv*16 + l15)*68 + ((ct & 3)*16) + quad*4;
        float s = tanh_fast(acc[0] + gb4.x) * khr[0]
                + tanh_fast(acc[1] + gb4.y) * khr[1]
                + tanh_fast(acc[2] + gb4.z) * khr[2]
                + tanh_fast(acc[3] + gb4.w) * khr[3];
        pacc += s;
        if ((ct & 3) == 3){
            pacc += __shfl_xor(pacc, 16, 64);
            pacc += __shfl_xor(pacc, 32, 64);
            if (quad == 0) dzl[(wv*16 + l15)*17 + (ct >> 2)] = pacc;
            pacc = 0.f;
        }
    }
    __syncthreads();

    // write-out + RK4 z bookkeeping: 4 nodes x 16 b x 16 i = 1024 values
#pragma unroll
    for (int it = 0; it < 4; it++){
        int e = it*256 + tid;
        int w = e >> 8, b = (e >> 4) & 15, il = e & 15;
        int nn = n0 + w;
        if (nn < NN){
            size_t addr = ((size_t)b*NN + nn)*64 + cg*16 + il;
            float v = dzl[(w*16 + b)*17 + il];
            kz[addr] = v;
            if (stage == 0)      accz[addr] = v;
            else if (stage < 3)  accz[addr] += 2.f*v;
            else                 z[addr] += (1.f/6.f)*(accz[addr] + v);
        }
    }
}

// ---------- output ----------
__global__ __launch_bounds__(256) void kOut(const float* __restrict__ z,
                                            const float* __restrict__ convW,
                                            const float* __restrict__ convB,
                                            float* __restrict__ out){
    int gid = blockIdx.x*256 + threadIdx.x;
    if (gid >= NB*NN) return;
    int b = gid / NN, n = gid % NN;
    float zr[64];
    const float4* zp = (const float4*)(z + (size_t)gid*64);
#pragma unroll
    for (int k4 = 0; k4 < 16; k4++){
        float4 v = zp[k4];
        zr[k4*4+0] = v.x; zr[k4*4+1] = v.y; zr[k4*4+2] = v.z; zr[k4*4+3] = v.w;
    }
#pragma unroll
    for (int o = 0; o < 12; o++){
        float acc = convB[o];
#pragma unroll
        for (int hh = 0; hh < 64; hh++) acc += zr[hh]*convW[o*64 + hh];
        out[(b*12 + o)*NN + n] = acc;
    }
}

extern "C" void kernel_launch(void* const* d_in, const int* in_sizes, int n_in,
                              void* d_out, int out_size, void* d_ws, size_t ws_size,
                              hipStream_t stream)
{
    const float* coeff_a = (const float*)d_in[0];
    const float* coeff_b = (const float*)d_in[1];
    const float* coeff_c = (const float*)d_in[2];
    const float* coeff_d = (const float*)d_in[3];
    const float* hW     = (const float*)d_in[5];
    const float* hb     = (const float*)d_in[6];
    const float* zW     = (const float*)d_in[7];
    const float* zb     = (const float*)d_in[8];
    const float* WfIn   = (const float*)d_in[9];
    const float* fbIn   = (const float*)d_in[10];
    const float* WfMid  = (const float*)d_in[11];
    const float* fbMid  = (const float*)d_in[12];
    const float* WfOut  = (const float*)d_in[13];
    const float* fbOut  = (const float*)d_in[14];
    const float* WgIn   = (const float*)d_in[15];
    const float* gbIn   = (const float*)d_in[16];
    const float* gE     = (const float*)d_in[17];
    const float* gWpool = (const float*)d_in[18];
    const float* gbpool = (const float*)d_in[19];
    const float* WgOut  = (const float*)d_in[20];
    const float* gbOut  = (const float*)d_in[21];
    const float* convW  = (const float*)d_in[22];
    const float* convB  = (const float*)d_in[23];

    float* ws = (float*)d_ws;
    unsigned short* Abf   = (unsigned short*)(ws + OFF_ABF);
    unsigned short* agcWt = (unsigned short*)(ws + OFF_AGCWT);
    float*          agcb  = ws + OFF_AGCB;
    unsigned short* Wtbf  = (unsigned short*)(ws + OFF_WT);
    float* h    = ws + OFF_H;
    float* z    = ws + OFF_Z;
    float* kh   = ws + OFF_KH;
    float* kz   = ws + OFF_KZ;
    float* acch = ws + OFF_ACCH;
    float* accz = ws + OFF_ACCZ;
    unsigned short* xbf  = (unsigned short*)(ws + OFF_XBF);
    unsigned short* xgbf = (unsigned short*)(ws + OFF_XGBF);
    float* out = (float*)d_out;

    kA     <<<320, 64,  0, stream>>>(gE, Abf);
    kAgcWT <<<NN,  256, 0, stream>>>(gE, gWpool, agcWt);
    kAgcB  <<<77,  256, 0, stream>>>(gE, gbpool, agcb);
    kWt    <<<64,  256, 0, stream>>>(WgOut, Wtbf);
    kInit  <<<1228,256, 0, stream>>>(coeff_a, hW, hb, zW, zb, h, z);

    const float acoef[4] = {0.f, 0.5f, 0.5f, 1.f};
    for (int step = 0; step < 11; step++){
        for (int s = 0; s < 4; s++){
            int idx; float frac;
            if (s == 0)      { idx = step;     frac = 0.f;  }
            else if (s < 3)  { idx = step;     frac = 0.5f; }
            else if (step<10){ idx = step + 1; frac = 0.f;  }
            else             { idx = 10;       frac = 1.f;  }
            K1 <<<1228, 256, 0, stream>>>(h, z, kh, kz, acch, xbf,
                coeff_b, coeff_c, coeff_d, WfIn, fbIn, WfMid, fbMid,
                WfOut, fbOut, WgIn, gbIn, s, acoef[s], idx, frac);
            KXG<<<320, 256, 0, stream>>>(xbf, Abf, xgbf);
            K2g<<<308, 256, 0, stream>>>(z, kh, kz, accz, xbf, xgbf,
                agcWt, agcb, Wtbf, gbOut, s);
        }
    }
    kOut<<<20, 256, 0, stream>>>(z, convW, convB, out);
}

// Round 4
// 2585.329 us; speedup vs baseline: 8.6340x; 1.4932x over previous
//
#include <hip/hip_runtime.h>

#define NB 16
#define NN 307
#define NI 11

typedef __attribute__((ext_vector_type(8))) short bf16x8;
typedef __attribute__((ext_vector_type(4))) float f32x4;

// ws offsets in FLOAT units
#define OFF_ABF    0u          // 320x320 bf16 = 51200 fl
#define OFF_AGCWT  51200u      // 307*64*128 bf16 = 1257472 fl
#define OFF_AGCB   1308672u    // 307*64 f32 -> pad 20480
#define OFF_WT     1329152u    // 4096*64 bf16 = 131072 fl
#define OFF_H      1460224u    // each state: 16*307*64 = 314368 fl
#define OFF_Z      1774592u
#define OFF_KH     2088960u
#define OFF_KZ     2403328u
#define OFF_ACCH   2717696u
#define OFF_ACCZ   3032064u
#define OFF_XBF    3346432u    // 320*16*64 bf16 = 163840 fl
#define OFF_XGBF   3510272u    // end 3674112 fl = 14.7 MB

__device__ __forceinline__ float tanh_fast(float x){
    float e = __expf(2.0f * x);
    return 1.0f - 2.0f * __builtin_amdgcn_rcpf(e + 1.0f);
}
__device__ __forceinline__ unsigned short f2bf(float f){
    unsigned u = __builtin_bit_cast(unsigned, f);
    unsigned r = u + 0x7FFFu + ((u >> 16) & 1u);
    return (unsigned short)(r >> 16);
}

// ---------- precompute ----------

// Abf[n][m] = bf16(softmax(relu(gE gE^T))) padded to 320x320 with zeros
__global__ void kA(const float* __restrict__ gE, unsigned short* __restrict__ Abf){
    int n = blockIdx.x;            // grid 320, 64 threads
    int lane = threadIdx.x;
    if (n >= NN){
#pragma unroll
        for (int ii = 0; ii < 5; ii++) Abf[n*320 + lane + 64*ii] = 0;
        return;
    }
    float en[8];
#pragma unroll
    for (int d = 0; d < 8; d++) en[d] = gE[n*8 + d];
    float vals[5];
    float mx = -1e30f;
#pragma unroll
    for (int ii = 0; ii < 5; ii++){
        int m = lane + 64*ii;
        float v = -1e30f;
        if (m < NN){
            float a = 0.f;
#pragma unroll
            for (int d = 0; d < 8; d++) a += en[d] * gE[m*8 + d];
            v = fmaxf(a, 0.f);
        }
        vals[ii] = v;
        mx = fmaxf(mx, v);
    }
#pragma unroll
    for (int off = 32; off >= 1; off >>= 1) mx = fmaxf(mx, __shfl_xor(mx, off, 64));
    float s = 0.f;
#pragma unroll
    for (int ii = 0; ii < 5; ii++){
        int m = lane + 64*ii;
        if (m < NN){ vals[ii] = __expf(vals[ii] - mx); s += vals[ii]; }
    }
#pragma unroll
    for (int off = 32; off >= 1; off >>= 1) s += __shfl_xor(s, off, 64);
    float inv = 1.f / s;
#pragma unroll
    for (int ii = 0; ii < 5; ii++){
        int m = lane + 64*ii;
        unsigned short v = 0;
        if (m < NN) v = f2bf(vals[ii] * inv);
        Abf[n*320 + m] = v;
    }
}

// agcWt[n][o][k] bf16, k = kk*64+i in [0,128)
__global__ __launch_bounds__(256) void kAgcWT(const float* __restrict__ gE,
                                              const float* __restrict__ gWpool,
                                              unsigned short* __restrict__ agcWt){
    __shared__ float t[128*65];
    int tid = threadIdx.x;
    int n = blockIdx.x;            // grid 307
    float ge[8];
#pragma unroll
    for (int d = 0; d < 8; d++) ge[d] = gE[n*8 + d];
    for (int it = 0; it < 32; it++){
        int e = it*256 + tid;      // [0,8192)
        int o = e & 63, i = (e >> 6) & 63, kk = e >> 12;
        float acc = 0.f;
#pragma unroll
        for (int d = 0; d < 8; d++) acc += ge[d] * gWpool[((size_t)(d*2 + kk)*64 + i)*64 + o];
        t[(kk*64 + i)*65 + o] = acc;
    }
    __syncthreads();
    for (int it = 0; it < 32; it++){
        int e = it*256 + tid;
        int k = e & 127, o = e >> 7;
        agcWt[((size_t)n*64 + o)*128 + k] = f2bf(t[k*65 + o]);
    }
}

__global__ void kAgcB(const float* __restrict__ gE, const float* __restrict__ gbpool,
                      float* __restrict__ agcb){
    int gid = blockIdx.x*256 + threadIdx.x;
    if (gid >= NN*64) return;
    int o = gid & 63;
    int n = gid >> 6;
    float acc = 0.f;
#pragma unroll
    for (int d = 0; d < 8; d++) acc += gE[n*8 + d] * gbpool[d*64 + o];
    agcb[gid] = acc;
}

// Wtbf[col][k] bf16 (transpose of WgOut[k][col])
__global__ __launch_bounds__(256) void kWt(const float* __restrict__ WgOut,
                                           unsigned short* __restrict__ Wtbf){
    __shared__ float t[64*65];
    int tid = threadIdx.x;
    int c0 = blockIdx.x*64;        // grid 64
    for (int it = 0; it < 16; it++){
        int e = it*256 + tid;
        int k = e >> 6, c = e & 63;
        t[k*65 + c] = WgOut[(size_t)k*4096 + c0 + c];
    }
    __syncthreads();
    for (int it = 0; it < 16; it++){
        int e = it*256 + tid;
        int c = e >> 6, k = e & 63;
        Wtbf[(size_t)(c0 + c)*64 + k] = f2bf(t[k*65 + c]);
    }
}

__global__ void kInit(const float* __restrict__ ca,
                      const float* __restrict__ hW, const float* __restrict__ hb,
                      const float* __restrict__ zW, const float* __restrict__ zb,
                      float* __restrict__ h, float* __restrict__ z){
    int gid = blockIdx.x*256 + threadIdx.x;   // exactly 314368
    int t = gid & 63;
    int bn = gid >> 6;
    float x0 = ca[bn*NI*2 + 0];
    float x1 = ca[bn*NI*2 + 1];
    h[gid] = x0*hW[t] + x1*hW[64 + t] + hb[t];
    z[gid] = x0*zW[t] + x1*zW[64 + t] + zb[t];
}

// ---------- K1: stage input, func_f MLP, kh, g-input x (bf16, node-major) ----------
// each wave owns its LDS slice -> no block barriers (within-wave LDS ordering via lgkmcnt)
__global__ __launch_bounds__(256) void K1(
    float* __restrict__ h, const float* __restrict__ z,
    float* __restrict__ kh, const float* __restrict__ kz,
    float* __restrict__ acch, unsigned short* __restrict__ xbf,
    const float* __restrict__ Cb, const float* __restrict__ Cc, const float* __restrict__ Cd,
    const float* __restrict__ WfIn, const float* __restrict__ fbIn,
    const float* __restrict__ WfMid, const float* __restrict__ fbMid,
    const float* __restrict__ WfOut, const float* __restrict__ fbOut,
    const float* __restrict__ WgIn, const float* __restrict__ gbIn,
    int stage, float acoef, int idx, float frac)
{
    __shared__ float4 bufA[4][16];
    __shared__ float4 bufB[4][16];
    __shared__ float4 bufZ[4][16];
    int tid = threadIdx.x;
    int wv = tid >> 6;
    int lane = tid & 63;
    int bn = blockIdx.x*4 + wv;            // b*307 + n
    int base = bn*64 + lane;
    unsigned ub = (unsigned)bn / 307u;
    int b = (int)ub;
    int n = bn - b*307;

    float hv = h[base];
    float zv = z[base];
    float sih = hv, siz = zv;
    if (stage > 0){ sih += acoef * kh[base]; siz += acoef * kz[base]; }
    ((float*)&bufA[wv][0])[lane] = sih;
    ((float*)&bufZ[wv][0])[lane] = siz;

    float u = fbIn[lane];
#pragma unroll
    for (int k4 = 0; k4 < 16; k4++){
        float4 s4 = bufA[wv][k4];
        int k = k4*4;
        u += s4.x*WfIn[(k+0)*64 + lane];
        u += s4.y*WfIn[(k+1)*64 + lane];
        u += s4.z*WfIn[(k+2)*64 + lane];
        u += s4.w*WfIn[(k+3)*64 + lane];
    }
    u = fmaxf(u, 0.f);
    ((float*)&bufB[wv][0])[lane] = u;

    float u2 = fbMid[lane];
#pragma unroll
    for (int k4 = 0; k4 < 16; k4++){
        float4 s4 = bufB[wv][k4];
        int k = k4*4;
        u2 += s4.x*WfMid[(k+0)*64 + lane];
        u2 += s4.y*WfMid[(k+1)*64 + lane];
        u2 += s4.z*WfMid[(k+2)*64 + lane];
        u2 += s4.w*WfMid[(k+3)*64 + lane];
    }
    u2 = fmaxf(u2, 0.f);
    ((float*)&bufA[wv][0])[lane] = u2;

    float f0 = fbOut[lane*2 + 0];
    float f1 = fbOut[lane*2 + 1];
    float xv = gbIn[lane];
#pragma unroll
    for (int k4 = 0; k4 < 16; k4++){
        float4 s4 = bufA[wv][k4];
        float4 z4 = bufZ[wv][k4];
        int k = k4*4;
        f0 += s4.x*WfOut[(k+0)*128 + lane*2+0]; f1 += s4.x*WfOut[(k+0)*128 + lane*2+1];
        f0 += s4.y*WfOut[(k+1)*128 + lane*2+0]; f1 += s4.y*WfOut[(k+1)*128 + lane*2+1];
        f0 += s4.z*WfOut[(k+2)*128 + lane*2+0]; f1 += s4.z*WfOut[(k+2)*128 + lane*2+1];
        f0 += s4.w*WfOut[(k+3)*128 + lane*2+0]; f1 += s4.w*WfOut[(k+3)*128 + lane*2+1];
        xv += z4.x*WgIn[(k+0)*64 + lane];
        xv += z4.y*WgIn[(k+1)*64 + lane];
        xv += z4.z*WgIn[(k+2)*64 + lane];
        xv += z4.w*WgIn[(k+3)*64 + lane];
    }
    f0 = tanh_fast(f0);
    f1 = tanh_fast(f1);

    int cb = (bn*NI + idx)*2;
    float b0 = Cb[cb], b1 = Cb[cb+1];
    float c0 = Cc[cb], c1 = Cc[cb+1];
    float d0 = Cd[cb], d1 = Cd[cb+1];
    float dx0 = b0 + (c0 + d0*frac)*frac;
    float dx1 = b1 + (c1 + d1*frac)*frac;

    float khv = f0*dx0 + f1*dx1;
    kh[base] = khv;
    if (stage == 0)      acch[base] = khv;
    else if (stage < 3)  acch[base] += 2.f*khv;
    else                 h[base] = hv + (1.f/6.f)*(acch[base] + khv);

    xbf[((size_t)n*16 + b)*64 + lane] = f2bf(fmaxf(xv, 0.f));
}

// ---------- KXG: xg = A @ x per batch, MFMA. grid 320 (b*20 + ntile) ----------
// stage whole X_b (64 c x 320 m) once; A-fragments preloaded to VGPRs.
__global__ __launch_bounds__(256) void KXG(
    const unsigned short* __restrict__ xbf, const unsigned short* __restrict__ Abf,
    unsigned short* __restrict__ xgbf)
{
    __shared__ unsigned short Xt[64*328];  // [c][m] pad 328 (row stride 164 dw == 4 mod 32)
    int tid = threadIdx.x, lane = tid & 63, wv = tid >> 6;
    int quad = lane >> 4, l15 = lane & 15;
    int b = blockIdx.x / 20, nt = blockIdx.x % 20;
    int n0 = nt*16;

    // preload A fragments (independent global loads)
    bf16x8 af[10];
#pragma unroll
    for (int mt = 0; mt < 10; mt++)
        af[mt] = *(const bf16x8*)(Abf + (size_t)(n0 + l15)*320 + mt*32 + quad*8);

    // stage X^T: 320 m x 8 segs of 8 c
#pragma unroll
    for (int it = 0; it < 10; it++){
        int e = it*256 + tid;          // [0,2560)
        int m = e >> 3, seg = e & 7;
        bf16x8 v = {0,0,0,0,0,0,0,0};
        if (m < NN) v = *(const bf16x8*)(xbf + ((size_t)m*16 + b)*64 + seg*8);
#pragma unroll
        for (int cc = 0; cc < 8; cc++)
            Xt[(seg*8 + cc)*328 + m] = ((unsigned short*)&v)[cc];
    }
    __syncthreads();

    f32x4 acc = {0.f,0.f,0.f,0.f};
#pragma unroll
    for (int mt = 0; mt < 10; mt++){
        bf16x8 bb = *(const bf16x8*)(Xt + (wv*16 + l15)*328 + mt*32 + quad*8);
        acc = __builtin_amdgcn_mfma_f32_16x16x32_bf16(af[mt], bb, acc, 0, 0, 0);
    }
    // D[n'=quad*4+r][c'=l15], wave wv owns c-tile wv*16
#pragma unroll
    for (int r = 0; r < 4; r++){
        int n = n0 + quad*4 + r;
        xgbf[((size_t)n*16 + b)*64 + wv*16 + l15] = f2bf(acc[r]);
    }
}

// ---------- K2g: per-node Y (MFMA) + Wt@Y^T GEMM from LDS + tanh*kh contraction ----------
// grid 77*16 = 1232 : nt = blk>>4 (4 nodes), cg = blk&15 (256 cols)
__global__ __launch_bounds__(256) void K2g(
    float* __restrict__ z, const float* __restrict__ kh,
    float* __restrict__ kz, float* __restrict__ accz,
    const unsigned short* __restrict__ xbf, const unsigned short* __restrict__ xgbf,
    const unsigned short* __restrict__ agcWt, const float* __restrict__ agcb,
    const unsigned short* __restrict__ Wtbf, const float* __restrict__ gbOut,
    int stage)
{
    __shared__ unsigned short WtL[256*72];    // [col_local][k] pad 72 -> 36 KB
    __shared__ unsigned short Ybf[4*16*72];   // [w][b][k] pad 72
    __shared__ float khl[4*16*68];            // [w][b][j] pad 68 (17 dw*4: stride 4 mod 32)
    __shared__ float dzl[4*16*5];             // [w][b][il] pad 5
    int tid = threadIdx.x, lane = tid & 63, wv = tid >> 6;
    int quad = lane >> 4, l15 = lane & 15;
    int nt = blockIdx.x >> 4, cg = blockIdx.x & 15;
    int n0 = nt*4;
    int nw = n0 + wv;
    int n = nw < NN ? nw : NN-1;
    int C0 = cg*256;

    // stage Wt slice (256 cols x 64 k) -> LDS, coalesced 16B per thread
#pragma unroll
    for (int it = 0; it < 8; it++){
        int e = it*256 + tid;      // 2048 segs
        int row = e >> 3, seg = e & 7;
        *(bf16x8*)(WtL + row*72 + seg*8) =
            *(const bf16x8*)(Wtbf + (size_t)(C0 + row)*64 + seg*8);
    }

    // khl: lane (quad=part, l15=b) loads 16 floats of kh[b][n][:]
    {
        const float* src = kh + ((size_t)l15*NN + n)*64 + quad*16;
        float* dst = khl + (wv*16 + l15)*68 + quad*16;
#pragma unroll
        for (int u2 = 0; u2 < 4; u2++)
            *(float4*)(dst + u2*4) = *(const float4*)(src + u2*4);
    }

    // Y-compute: Y_n[b][o] = relu(Xcat_n @ agcWt_n + agcb_n)
    const size_t xrow = ((size_t)n*16 + l15)*64;
#pragma unroll
    for (int ot = 0; ot < 4; ot++){
        f32x4 acc = {0.f,0.f,0.f,0.f};
#pragma unroll
        for (int kt = 0; kt < 4; kt++){
            bf16x8 a;
            if (kt < 2) a = *(const bf16x8*)(xbf  + xrow + kt*32 + quad*8);
            else        a = *(const bf16x8*)(xgbf + xrow + (kt-2)*32 + quad*8);
            bf16x8 bb = *(const bf16x8*)(agcWt + ((size_t)n*64 + ot*16 + l15)*128 + kt*32 + quad*8);
            acc = __builtin_amdgcn_mfma_f32_16x16x32_bf16(a, bb, acc, 0, 0, 0);
        }
        float gb = agcb[n*64 + ot*16 + l15];
#pragma unroll
        for (int r = 0; r < 4; r++){
            float v = fmaxf(acc[r] + gb, 0.f);
            Ybf[(wv*16 + quad*4 + r)*72 + ot*16 + l15] = f2bf(v);
        }
    }
    __syncthreads();   // WtL is cross-wave; Ybf/khl are own-wave

    // GEMM: D[col_local][b]; cols C0..C0+255; fuse tanh, *kh, j-reduction
    float pacc = 0.f;
#pragma unroll
    for (int ct = 0; ct < 16; ct++){
        f32x4 acc = {0.f,0.f,0.f,0.f};
#pragma unroll
        for (int kt = 0; kt < 2; kt++){
            bf16x8 a  = *(const bf16x8*)(WtL + (ct*16 + l15)*72 + kt*32 + quad*8);
            bf16x8 bb = *(const bf16x8*)(Ybf + (wv*16 + l15)*72 + kt*32 + quad*8);
            acc = __builtin_amdgcn_mfma_f32_16x16x32_bf16(a, bb, acc, 0, 0, 0);
        }
        float4 gb4 = *(const float4*)(gbOut + C0 + ct*16 + quad*4);
        float4 kh4 = *(const float4*)(khl + (wv*16 + l15)*68 + (ct & 3)*16 + quad*4);
        float s = tanh_fast(acc[0] + gb4.x) * kh4.x
                + tanh_fast(acc[1] + gb4.y) * kh4.y
                + tanh_fast(acc[2] + gb4.z) * kh4.z
                + tanh_fast(acc[3] + gb4.w) * kh4.w;
        pacc += s;
        if ((ct & 3) == 3){
            pacc += __shfl_xor(pacc, 16, 64);
            pacc += __shfl_xor(pacc, 32, 64);
            if (quad == 0) dzl[(wv*16 + l15)*5 + (ct >> 2)] = pacc;
            pacc = 0.f;
        }
    }
    // dzl written & read by the same wave -> no barrier needed

    // write-out + RK4 z bookkeeping: 4 nodes x 16 b x 4 i = 256 values
    {
        int w = tid >> 6, bb_ = (tid >> 2) & 15, il = tid & 3;
        int nn = n0 + w;
        if (nn < NN){
            size_t addr = ((size_t)bb_*NN + nn)*64 + cg*4 + il;
            float v = dzl[(w*16 + bb_)*5 + il];
            kz[addr] = v;
            if (stage == 0)      accz[addr] = v;
            else if (stage < 3)  accz[addr] += 2.f*v;
            else                 z[addr] += (1.f/6.f)*(accz[addr] + v);
        }
    }
}

// ---------- output ----------
__global__ __launch_bounds__(256) void kOut(const float* __restrict__ z,
                                            const float* __restrict__ convW,
                                            const float* __restrict__ convB,
                                            float* __restrict__ out){
    int gid = blockIdx.x*256 + threadIdx.x;
    if (gid >= NB*NN) return;
    int b = gid / NN, n = gid % NN;
    float zr[64];
    const float4* zp = (const float4*)(z + (size_t)gid*64);
#pragma unroll
    for (int k4 = 0; k4 < 16; k4++){
        float4 v = zp[k4];
        zr[k4*4+0] = v.x; zr[k4*4+1] = v.y; zr[k4*4+2] = v.z; zr[k4*4+3] = v.w;
    }
#pragma unroll
    for (int o = 0; o < 12; o++){
        float acc = convB[o];
#pragma unroll
        for (int hh = 0; hh < 64; hh++) acc += zr[hh]*convW[o*64 + hh];
        out[(b*12 + o)*NN + n] = acc;
    }
}

extern "C" void kernel_launch(void* const* d_in, const int* in_sizes, int n_in,
                              void* d_out, int out_size, void* d_ws, size_t ws_size,
                              hipStream_t stream)
{
    const float* coeff_a = (const float*)d_in[0];
    const float* coeff_b = (const float*)d_in[1];
    const float* coeff_c = (const float*)d_in[2];
    const float* coeff_d = (const float*)d_in[3];
    const float* hW     = (const float*)d_in[5];
    const float* hb     = (const float*)d_in[6];
    const float* zW     = (const float*)d_in[7];
    const float* zb     = (const float*)d_in[8];
    const float* WfIn   = (const float*)d_in[9];
    const float* fbIn   = (const float*)d_in[10];
    const float* WfMid  = (const float*)d_in[11];
    const float* fbMid  = (const float*)d_in[12];
    const float* WfOut  = (const float*)d_in[13];
    const float* fbOut  = (const float*)d_in[14];
    const float* WgIn   = (const float*)d_in[15];
    const float* gbIn   = (const float*)d_in[16];
    const float* gE     = (const float*)d_in[17];
    const float* gWpool = (const float*)d_in[18];
    const float* gbpool = (const float*)d_in[19];
    const float* WgOut  = (const float*)d_in[20];
    const float* gbOut  = (const float*)d_in[21];
    const float* convW  = (const float*)d_in[22];
    const float* convB  = (const float*)d_in[23];

    float* ws = (float*)d_ws;
    unsigned short* Abf   = (unsigned short*)(ws + OFF_ABF);
    unsigned short* agcWt = (unsigned short*)(ws + OFF_AGCWT);
    float*          agcb  = ws + OFF_AGCB;
    unsigned short* Wtbf  = (unsigned short*)(ws + OFF_WT);
    float* h    = ws + OFF_H;
    float* z    = ws + OFF_Z;
    float* kh   = ws + OFF_KH;
    float* kz   = ws + OFF_KZ;
    float* acch = ws + OFF_ACCH;
    float* accz = ws + OFF_ACCZ;
    unsigned short* xbf  = (unsigned short*)(ws + OFF_XBF);
    unsigned short* xgbf = (unsigned short*)(ws + OFF_XGBF);
    float* out = (float*)d_out;

    kA     <<<320, 64,  0, stream>>>(gE, Abf);
    kAgcWT <<<NN,  256, 0, stream>>>(gE, gWpool, agcWt);
    kAgcB  <<<77,  256, 0, stream>>>(gE, gbpool, agcb);
    kWt    <<<64,  256, 0, stream>>>(WgOut, Wtbf);
    kInit  <<<1228,256, 0, stream>>>(coeff_a, hW, hb, zW, zb, h, z);

    const float acoef[4] = {0.f, 0.5f, 0.5f, 1.f};
    for (int step = 0; step < 11; step++){
        for (int s = 0; s < 4; s++){
            int idx; float frac;
            if (s == 0)      { idx = step;     frac = 0.f;  }
            else if (s < 3)  { idx = step;     frac = 0.5f; }
            else if (step<10){ idx = step + 1; frac = 0.f;  }
            else             { idx = 10;       frac = 1.f;  }
            K1 <<<1228, 256, 0, stream>>>(h, z, kh, kz, acch, xbf,
                coeff_b, coeff_c, coeff_d, WfIn, fbIn, WfMid, fbMid,
                WfOut, fbOut, WgIn, gbIn, s, acoef[s], idx, frac);
            KXG<<<320, 256, 0, stream>>>(xbf, Abf, xgbf);
            K2g<<<1232, 256, 0, stream>>>(z, kh, kz, accz, xbf, xgbf,
                agcWt, agcb, Wtbf, gbOut, s);
        }
    }
    kOut<<<20, 256, 0, stream>>>(z, convW, convB, out);
}